// Round 4
// baseline (441.117 us; speedup 1.0000x reference)
//
#include <hip/hip_runtime.h>

typedef float f32x4 __attribute__((ext_vector_type(4)));
typedef __bf16 bf16x8 __attribute__((ext_vector_type(8)));
typedef unsigned short u16x8 __attribute__((ext_vector_type(8)));
typedef unsigned short u16x4 __attribute__((ext_vector_type(4)));

#define AS1 __attribute__((address_space(1)))
#define AS3 __attribute__((address_space(3)))

static __device__ __forceinline__ void gll16(const void* g, void* l) {
  // async global->LDS DMA, 16B/lane; LDS dest = wave-uniform base + lane*16
  __builtin_amdgcn_global_load_lds((const AS1 void*)g, (AS3 void*)l, 16, 0, 0);
}

static __device__ __forceinline__ float bf2f(unsigned short u) {
  unsigned int x = ((unsigned int)u) << 16;
  float f; __builtin_memcpy(&f, &x, 4); return f;
}
// native RNE f32->bf16 (compiler emits packed cvt; identical rounding to the
// manual bit-twiddle for finite values, ~4x fewer VALU ops)
static __device__ __forceinline__ unsigned short f2bf(float f) {
  __bf16 h = (__bf16)f;
  unsigned short u; __builtin_memcpy(&u, &h, 2); return u;
}

#define LOG2E 1.4426950408889634f
// fold 1/sqrt(HD)=0.125 and log2(e) into stored q
#define QSCALE (0.125f * LOG2E)

// ---------------------------------------------------------------------------
// Kernel: convert x fp32 -> bf16 (elementwise).  4096x1024
// ---------------------------------------------------------------------------
__global__ __launch_bounds__(256) void k_cvt_x(const float* __restrict__ x,
                                               unsigned short* __restrict__ xb) {
  int i = (blockIdx.x * 256 + threadIdx.x) * 4;
  float4 v = *(const float4*)(x + i);
  u16x4 o; o.x = f2bf(v.x); o.y = f2bf(v.y); o.z = f2bf(v.z); o.w = f2bf(v.w);
  *(u16x4*)(xb + i) = o;
}

// ---------------------------------------------------------------------------
// Kernel: transpose 1024x1024 fp32 -> bf16 [n][k].  z: 0=Wq 1=Wk 2=Wv 3=Wo
// ---------------------------------------------------------------------------
__global__ __launch_bounds__(256) void k_transpose(const float* __restrict__ w0,
                                                   const float* __restrict__ w1,
                                                   const float* __restrict__ w2,
                                                   const float* __restrict__ w3,
                                                   unsigned short* __restrict__ dqkv,
                                                   unsigned short* __restrict__ dwo) {
  __shared__ float tile[32][33];
  int z = blockIdx.z;
  const float* src = (z == 0) ? w0 : (z == 1) ? w1 : (z == 2) ? w2 : w3;
  unsigned short* dst = (z < 3) ? (dqkv + (size_t)z * 1024 * 1024) : dwo;
  int tx = threadIdx.x, ty = threadIdx.y;
  int x0 = blockIdx.x * 32, y0 = blockIdx.y * 32;
#pragma unroll
  for (int i = 0; i < 4; ++i)
    tile[ty + 8 * i][tx] = src[(size_t)(y0 + ty + 8 * i) * 1024 + x0 + tx];
  __syncthreads();
#pragma unroll
  for (int i = 0; i < 4; ++i)
    dst[(size_t)(x0 + ty + 8 * i) * 1024 + y0 + tx] = f2bf(tile[tx][ty + 8 * i]);
}

// ---------------------------------------------------------------------------
// Kernel: bias[h][q][k] = log2e * sum_c R[c][h] * Qb[q][k][c]   (bf16 out)
// grid: 2048 blocks (q), 256 threads; thread t covers k = t*8 .. t*8+7
// ---------------------------------------------------------------------------
__global__ __launch_bounds__(256) void k_bias(const float* __restrict__ Qb,
                                              const float* __restrict__ R,
                                              unsigned short* __restrict__ bias) {
  __shared__ float Rs[8][16];
  int t = threadIdx.x;
  if (t < 128) Rs[t >> 4][t & 15] = R[t] * LOG2E;
  __syncthreads();
  int q = blockIdx.x;
  int k = t * 8;
  const float* src = Qb + ((size_t)q * 2048 + k) * 8;  // 64 contiguous floats
  float a[8][8];
#pragma unroll
  for (int kk = 0; kk < 8; ++kk) {
    float4 lo = *(const float4*)(src + kk * 8);
    float4 hi = *(const float4*)(src + kk * 8 + 4);
    a[kk][0] = lo.x; a[kk][1] = lo.y; a[kk][2] = lo.z; a[kk][3] = lo.w;
    a[kk][4] = hi.x; a[kk][5] = hi.y; a[kk][6] = hi.z; a[kk][7] = hi.w;
  }
#pragma unroll
  for (int h = 0; h < 16; ++h) {
    u16x8 o;
#pragma unroll
    for (int kk = 0; kk < 8; ++kk) {
      float s = 0.f;
#pragma unroll
      for (int c = 0; c < 8; ++c) s += a[kk][c] * Rs[c][h];
      o[kk] = f2bf(s);
    }
    *(u16x8*)(bias + ((size_t)h * 2048 + q) * 2048 + k) = o;
  }
}

// ---------------------------------------------------------------------------
// Kernel: QKV GEMM  C[4096][3072] = x_bf16[4096][1024] @ Wqkv_t^T  + fused QK-LN
// 2-phase double-buffered staging: DMA for kt+1 issued before compute of kt,
// one barrier per K-step (vmcnt drain overlapped with MFMA phase).
// V is now written in NATURAL layout [b][h][s][hd] (same 32B-granular store
// pattern as Q/K).  The old direct V^T write was 2B stores at 4KB stride:
// 64 cachelines per wave-store -> ~32x write-allocate amplification.  k_vt
// does the transpose properly through LDS.
// ---------------------------------------------------------------------------
__global__ __launch_bounds__(256) void k_qkv(const unsigned short* __restrict__ xb,
                                             const unsigned short* __restrict__ wt,
                                             const float* __restrict__ bq,
                                             const float* __restrict__ bk,
                                             const float* __restrict__ bv,
                                             const float* __restrict__ qls,
                                             const float* __restrict__ kls,
                                             unsigned short* __restrict__ qo,
                                             unsigned short* __restrict__ kqo,
                                             unsigned short* __restrict__ vo) {
  __shared__ __align__(16) unsigned short As[8192];  // 2 x [128 m][32 k]
  __shared__ __align__(16) unsigned short Bs[8192];  // 2 x [128 n][32 k]
  const int tid = threadIdx.x;
  const int w = tid >> 6, lane = tid & 63, quad = lane >> 4, lx = lane & 15;
  const int m0 = blockIdx.y * 128, n0 = blockIdx.x * 128;
  const int wrow = w >> 1, wcol = w & 1;

  f32x4 acc[4][4];
#pragma unroll
  for (int i = 0; i < 4; ++i)
#pragma unroll
    for (int j = 0; j < 4; ++j) acc[i][j] = (f32x4){0.f, 0.f, 0.f, 0.f};

  const unsigned short* ga = xb + (size_t)(m0 + 32 * w + (lane >> 2)) * 1024 + (lane & 3) * 8;
  const unsigned short* gb = wt + (size_t)(n0 + 32 * w + (lane >> 2)) * 1024 + (lane & 3) * 8;

  // prologue: stage kt=0 into buffer 0
  gll16(ga, As + w * 1024);
  gll16(ga + 16 * 1024, As + w * 1024 + 512);
  gll16(gb, Bs + w * 1024);
  gll16(gb + 16 * 1024, Bs + w * 1024 + 512);
  __syncthreads();

  for (int kt = 0; kt < 32; ++kt) {
    const int cur = kt & 1;
    if (kt < 31) {
      const int kofs = (kt + 1) * 32;
      unsigned short* lan = As + (cur ^ 1) * 4096 + w * 1024;
      unsigned short* lbn = Bs + (cur ^ 1) * 4096 + w * 1024;
      gll16(ga + kofs, lan);
      gll16(ga + kofs + 16 * 1024, lan + 512);
      gll16(gb + kofs, lbn);
      gll16(gb + kofs + 16 * 1024, lbn + 512);
    }
    const unsigned short* ac = As + cur * 4096;
    const unsigned short* bc = Bs + cur * 4096;
    bf16x8 af[4], bfr[4];
#pragma unroll
    for (int i = 0; i < 4; ++i)
      af[i] = *(const bf16x8*)&ac[(64 * wrow + 16 * i + lx) * 32 + quad * 8];
#pragma unroll
    for (int j = 0; j < 4; ++j)
      bfr[j] = *(const bf16x8*)&bc[(64 * wcol + 16 * j + lx) * 32 + quad * 8];
    __builtin_amdgcn_s_setprio(1);
#pragma unroll
    for (int i = 0; i < 4; ++i)
#pragma unroll
      for (int j = 0; j < 4; ++j)
        acc[i][j] = __builtin_amdgcn_mfma_f32_16x16x32_bf16(af[i], bfr[j], acc[i][j], 0, 0, 0);
    __builtin_amdgcn_s_setprio(0);
    __syncthreads();
  }

  const int colbase = n0 + 64 * wcol;
  const int region = colbase >> 10;         // 0=q 1=k 2=v
  const int h = (colbase & 1023) >> 6;
  const float* pbp = (region == 0) ? bq : (region == 1) ? bk : bv;
  float pb[4];
#pragma unroll
  for (int j = 0; j < 4; ++j) pb[j] = pbp[h * 64 + j * 16 + lx];

  if (region == 2) {
    // natural layout [b][h][s][hd]; k_vt transposes afterwards
#pragma unroll
    for (int i = 0; i < 4; ++i) {
#pragma unroll
      for (int rr = 0; rr < 4; ++rr) {
        int m = m0 + 64 * wrow + 16 * i + quad * 4 + rr;
        int b = m >> 11, s = m & 2047;
        unsigned short* dst = vo + (((size_t)b * 16 + h) * 2048 + s) * 64;
#pragma unroll
        for (int j = 0; j < 4; ++j) dst[j * 16 + lx] = f2bf(acc[i][j][rr] + pb[j]);
      }
    }
  } else {
    const float fac = region ? 1.0f : QSCALE;
    float scl[4];
    const float* lsp = region ? kls : qls;
#pragma unroll
    for (int j = 0; j < 4; ++j) scl[j] = lsp[j * 16 + lx] * fac;
    unsigned short* base = region ? kqo : qo;
#pragma unroll
    for (int i = 0; i < 4; ++i) {
#pragma unroll
      for (int rr = 0; rr < 4; ++rr) {
        int m = m0 + 64 * wrow + 16 * i + quad * 4 + rr;
        int b = m >> 11, s = m & 2047;
        float v0 = acc[i][0][rr] + pb[0];
        float v1 = acc[i][1][rr] + pb[1];
        float v2 = acc[i][2][rr] + pb[2];
        float v3 = acc[i][3][rr] + pb[3];
        float s1 = v0 + v1 + v2 + v3;
        float s2 = v0 * v0 + v1 * v1 + v2 * v2 + v3 * v3;
#pragma unroll
        for (int d = 1; d < 16; d <<= 1) {
          s1 += __shfl_xor(s1, d, 64);
          s2 += __shfl_xor(s2, d, 64);
        }
        float mu = s1 * 0.015625f;
        float var = s2 * 0.015625f - mu * mu;
        float ri = __builtin_amdgcn_rsqf(var + 1e-6f);
        unsigned short* dst = base + (((size_t)b * 16 + h) * 2048 + s) * 64;
        dst[0 * 16 + lx] = f2bf((v0 - mu) * ri * scl[0]);
        dst[1 * 16 + lx] = f2bf((v1 - mu) * ri * scl[1]);
        dst[2 * 16 + lx] = f2bf((v2 - mu) * ri * scl[2]);
        dst[3 * 16 + lx] = f2bf((v3 - mu) * ri * scl[3]);
      }
    }
  }
}

// ---------------------------------------------------------------------------
// Kernel: V transpose  [bh][2048 s][64 d] -> [bh][64 d][2048 s]  (bf16)
// LDS as u32 d-pairs [32 dpair][65 s-pad]: load-phase writes 2-way-conflict
// free, transposed reads 2-way free (65 ≡ 1 mod 32 spreads banks).  Both
// global sides fully coalesced (128B per 8-lane group).  32 MB traffic.
// ---------------------------------------------------------------------------
__global__ __launch_bounds__(256) void k_vt(const unsigned short* __restrict__ in,
                                            unsigned short* __restrict__ out) {
  __shared__ unsigned int ls[32][65];
  const int t = threadIdx.x;
  const int s0 = blockIdx.x * 64;
  const int bh = blockIdx.y;
  const unsigned short* src = in + ((size_t)bh * 2048 + s0) * 64;
  const int sr = t >> 3, dp0 = (t & 7) * 4;
#pragma unroll
  for (int p = 0; p < 2; ++p) {
    const int s = sr + 32 * p;
    uint4 v = *(const uint4*)(src + (size_t)s * 64 + dp0 * 2);
    ls[dp0 + 0][s] = v.x;
    ls[dp0 + 1][s] = v.y;
    ls[dp0 + 2][s] = v.z;
    ls[dp0 + 3][s] = v.w;
  }
  __syncthreads();
  const int dp = t >> 3, sc = (t & 7) * 8;
  unsigned int a[8];
#pragma unroll
  for (int i = 0; i < 8; ++i) a[i] = ls[dp][sc + i];
  u16x8 lo, hi;
#pragma unroll
  for (int i = 0; i < 8; ++i) {
    lo[i] = (unsigned short)(a[i] & 0xffffu);
    hi[i] = (unsigned short)(a[i] >> 16);
  }
  unsigned short* dst = out + ((size_t)bh * 64 + 2 * dp) * 2048 + s0 + sc;
  *(u16x8*)dst = lo;
  *(u16x8*)(dst + 2048) = hi;
}

// ---------------------------------------------------------------------------
// Kernel: flash attention, fixed-reference softmax (scores provably bounded:
// |qk|/8*log2e <= 11.6, |bias| small => exp2 never overflows fp32).
// 2-phase double-buffered K/V staging (DMA for kt+1 issued before compute of
// kt; ONE barrier per K-tile, vmcnt drain hidden under QK+softmax+PV).
// P buffer overlaid on Q staging LDS (both per-wave-private; Q consumed into
// registers in prologue).  P layout [16q][64k]/wave, XOR chunk-swizzle
// (phys = logical ^ (q&7)) -> conflict-profile equal to a padded layout.
// LDS total = 8KB(QP) + 16KB(K x2) + 16KB(V x2) = 40960B; 4 blocks/CU exact.
// (Unchanged this round - frozen for attribution.)
// ---------------------------------------------------------------------------
__global__ __launch_bounds__(256) void k_attn(const unsigned short* __restrict__ qp,
                                              const unsigned short* __restrict__ kp,
                                              const unsigned short* __restrict__ vp,
                                              const unsigned short* __restrict__ bp,
                                              unsigned short* __restrict__ ctx) {
  __shared__ __align__(16) unsigned short QPs[4096]; // Q stage, then per-wave P (swizzled)
  __shared__ __align__(16) unsigned short Ks[8192];  // 2 x [64 key][64 hd] swizzled chunks
  __shared__ __align__(16) unsigned short Vs[8192];  // 2 x [64 hd][64 key] swizzled chunks
  const int tid = threadIdx.x;
  const int w = tid >> 6, lane = tid & 63, quad = lane >> 4, lx = lane & 15;
  const int lx7 = lane & 7;
  const int qt = blockIdx.x, h = blockIdx.y, b = blockIdx.z;
  const int q0 = qt * 64;
  const size_t bh = (size_t)b * 16 + h;

  // stage Q (contiguous 8KB, natural layout; consumed into regs after barrier)
  const unsigned short* qg = qp + (bh * 2048 + q0) * 64;
  gll16(qg + w * 512 + lane * 8, QPs + w * 512);
  gll16(qg + 2048 + w * 512 + lane * 8, QPs + 2048 + w * 512);

  const unsigned short* kg = kp + bh * 2048 * 64;
  const unsigned short* vg = vp + bh * 64 * 2048;
  const unsigned short* bg = bp + ((size_t)h * 2048 + q0 + 16 * w + quad * 4) * 2048 + lx;

  // DMA source for swizzled staging: lane covers (row=16w+(lane>>3)(+8), chunk=lane&7)
  const int rA = 16 * w + (lane >> 3);
  const int cA = (lane & 7) ^ (rA & 7);          // logical chunk fetched into phys slot lane&7
  const unsigned short* kgA = kg + (size_t)rA * 64 + cA * 8;        // + k0*64 per tile
  const unsigned short* kgB = kg + (size_t)(rA + 8) * 64 + cA * 8;
  const unsigned short* vgA = vg + (size_t)rA * 2048 + cA * 8;      // + k0 per tile
  const unsigned short* vgB = vg + (size_t)(rA + 8) * 2048 + cA * 8;

  // prologue: stage kt=0 K/V into buffer 0, load kt=0 bias fragments
  gll16(kgA, Ks + w * 1024);
  gll16(kgB, Ks + w * 1024 + 512);
  gll16(vgA, Vs + w * 1024);
  gll16(vgB, Vs + w * 1024 + 512);
  unsigned short bu[4][4], bun[4][4];
#pragma unroll
  for (int rr = 0; rr < 4; ++rr)
#pragma unroll
    for (int j = 0; j < 4; ++j) bu[rr][j] = bg[(size_t)rr * 2048 + j * 16];

  __syncthreads();

  bf16x8 qf[2];
#pragma unroll
  for (int hh = 0; hh < 2; ++hh)
    qf[hh] = *(const bf16x8*)&QPs[(16 * w + lx) * 64 + hh * 32 + quad * 8];

  float l_run[4] = {0.f, 0.f, 0.f, 0.f};
  f32x4 acco[4];
#pragma unroll
  for (int j = 0; j < 4; ++j) acco[j] = (f32x4){0.f, 0.f, 0.f, 0.f};

  for (int kt = 0; kt < 32; ++kt) {
    const int cur = kt & 1;
    const unsigned short* kc = Ks + cur * 4096;
    const unsigned short* vc = Vs + cur * 4096;
    // issue next tile's DMA + bias prefetch before computing current tile
    if (kt < 31) {
      const size_t k1 = (size_t)(kt + 1) * 64;
      unsigned short* kn = Ks + (cur ^ 1) * 4096 + w * 1024;
      unsigned short* vn = Vs + (cur ^ 1) * 4096 + w * 1024;
      gll16(kgA + k1 * 64, kn);
      gll16(kgB + k1 * 64, kn + 512);
      gll16(vgA + k1, vn);
      gll16(vgB + k1, vn + 512);
#pragma unroll
      for (int rr = 0; rr < 4; ++rr)
#pragma unroll
        for (int j = 0; j < 4; ++j) bun[rr][j] = bg[(size_t)rr * 2048 + k1 + j * 16];
    }

    f32x4 accs[4];
#pragma unroll
    for (int j = 0; j < 4; ++j)
#pragma unroll
      for (int rr = 0; rr < 4; ++rr) accs[j][rr] = bf2f(bu[rr][j]);
    __builtin_amdgcn_s_setprio(1);
#pragma unroll
    for (int j = 0; j < 4; ++j) {
#pragma unroll
      for (int hh = 0; hh < 2; ++hh) {
        bf16x8 kf = *(const bf16x8*)&kc[(j * 16 + lx) * 64 + ((hh * 4 + quad) ^ lx7) * 8];
        accs[j] = __builtin_amdgcn_mfma_f32_16x16x32_bf16(qf[hh], kf, accs[j], 0, 0, 0);
      }
    }
    __builtin_amdgcn_s_setprio(0);

    // fixed-reference softmax: p = exp2(score), per-lane partial l, no max
#pragma unroll
    for (int rr = 0; rr < 4; ++rr) {
      float p0 = __builtin_amdgcn_exp2f(accs[0][rr]);
      float p1 = __builtin_amdgcn_exp2f(accs[1][rr]);
      float p2 = __builtin_amdgcn_exp2f(accs[2][rr]);
      float p3 = __builtin_amdgcn_exp2f(accs[3][rr]);
      l_run[rr] += (p0 + p1) + (p2 + p3);
      // P write: q=quad*4+rr, k=lx+16j; phys chunk = (k>>3) ^ (q&7)
      const int q = quad * 4 + rr;
      const int swz = q & 7;
      const int ch = lx >> 3;
      unsigned short* pw = QPs + w * 1024 + q * 64 + (lx & 7);
      pw[((ch ^ swz) << 3)]       = f2bf(p0);
      pw[(((ch + 2) ^ swz) << 3)] = f2bf(p1);
      pw[(((ch + 4) ^ swz) << 3)] = f2bf(p2);
      pw[(((ch + 6) ^ swz) << 3)] = f2bf(p3);
    }
    __asm__ volatile("s_waitcnt lgkmcnt(0)" ::: "memory");
    bf16x8 pf[2];
#pragma unroll
    for (int kh = 0; kh < 2; ++kh)
      pf[kh] = *(const bf16x8*)&QPs[w * 1024 + lx * 64 + (((kh * 4 + quad) ^ (lx & 7)) << 3)];
    __builtin_amdgcn_s_setprio(1);
#pragma unroll
    for (int j = 0; j < 4; ++j) {
#pragma unroll
      for (int kh = 0; kh < 2; ++kh) {
        bf16x8 vf = *(const bf16x8*)&vc[(j * 16 + lx) * 64 + ((kh * 4 + quad) ^ lx7) * 8];
        acco[j] = __builtin_amdgcn_mfma_f32_16x16x32_bf16(pf[kh], vf, acco[j], 0, 0, 0);
      }
    }
    __builtin_amdgcn_s_setprio(0);
    __syncthreads();   // waves done with buf[cur]; DMA into buf[cur^1] drained here
#pragma unroll
    for (int rr = 0; rr < 4; ++rr)
#pragma unroll
      for (int j = 0; j < 4; ++j) bu[rr][j] = bun[rr][j];
  }

  // epilogue: one cross-lane l reduction, O /= l, write ctx[b][s][h][hd] bf16
#pragma unroll
  for (int rr = 0; rr < 4; ++rr) {
    float l = l_run[rr];
#pragma unroll
    for (int d = 1; d < 16; d <<= 1) l += __shfl_xor(l, d, 64);
    float rl = __builtin_amdgcn_rcpf(l);
    int s = q0 + 16 * w + quad * 4 + rr;
    unsigned short* dst = ctx + (((size_t)b * 2048 + s) * 16 + h) * 64;
#pragma unroll
    for (int j = 0; j < 4; ++j) dst[j * 16 + lx] = f2bf(acco[j][rr] * rl);
  }
}

// ---------------------------------------------------------------------------
// Kernel: output GEMM  out[4096][1024] = ctx[4096][1024] @ Wo_t^T + bo  (fp32)
// 128x64 tiles -> 512 blocks (2 blocks/CU).  24KB LDS double-buffered.
// ---------------------------------------------------------------------------
__global__ __launch_bounds__(256) void k_out(const unsigned short* __restrict__ cx,
                                             const unsigned short* __restrict__ wt,
                                             const float* __restrict__ bo,
                                             float* __restrict__ out) {
  __shared__ __align__(16) unsigned short As[8192];  // 2 x [128 m][32 k]
  __shared__ __align__(16) unsigned short Bs[4096];  // 2 x [ 64 n][32 k]
  const int tid = threadIdx.x;
  const int w = tid >> 6, lane = tid & 63, quad = lane >> 4, lx = lane & 15;
  const int m0 = blockIdx.y * 128, n0 = blockIdx.x * 64;
  const int wrow = w >> 1, wcol = w & 1;

  f32x4 acc[4][2];
#pragma unroll
  for (int i = 0; i < 4; ++i)
#pragma unroll
    for (int j = 0; j < 2; ++j) acc[i][j] = (f32x4){0.f, 0.f, 0.f, 0.f};

  const unsigned short* ga = cx + (size_t)(m0 + 32 * w + (lane >> 2)) * 1024 + (lane & 3) * 8;
  const unsigned short* gb = wt + (size_t)(n0 + 16 * w + (lane >> 2)) * 1024 + (lane & 3) * 8;

  gll16(ga, As + w * 1024);
  gll16(ga + 16 * 1024, As + w * 1024 + 512);
  gll16(gb, Bs + w * 512);
  __syncthreads();

  for (int kt = 0; kt < 32; ++kt) {
    const int cur = kt & 1;
    if (kt < 31) {
      const int kofs = (kt + 1) * 32;
      unsigned short* lan = As + (cur ^ 1) * 4096 + w * 1024;
      gll16(ga + kofs, lan);
      gll16(ga + kofs + 16 * 1024, lan + 512);
      gll16(gb + kofs, Bs + (cur ^ 1) * 2048 + w * 512);
    }
    const unsigned short* ac = As + cur * 4096;
    const unsigned short* bc = Bs + cur * 2048;
    bf16x8 af[4], bfr[2];
#pragma unroll
    for (int i = 0; i < 4; ++i)
      af[i] = *(const bf16x8*)&ac[(64 * wrow + 16 * i + lx) * 32 + quad * 8];
#pragma unroll
    for (int j = 0; j < 2; ++j)
      bfr[j] = *(const bf16x8*)&bc[(32 * wcol + 16 * j + lx) * 32 + quad * 8];
    __builtin_amdgcn_s_setprio(1);
#pragma unroll
    for (int i = 0; i < 4; ++i)
#pragma unroll
      for (int j = 0; j < 2; ++j)
        acc[i][j] = __builtin_amdgcn_mfma_f32_16x16x32_bf16(af[i], bfr[j], acc[i][j], 0, 0, 0);
    __builtin_amdgcn_s_setprio(0);
    __syncthreads();
  }

  const int colbase = n0 + 32 * wcol;
  float bb[2];
#pragma unroll
  for (int j = 0; j < 2; ++j) bb[j] = bo[colbase + j * 16 + lx];
#pragma unroll
  for (int i = 0; i < 4; ++i) {
#pragma unroll
    for (int rr = 0; rr < 4; ++rr) {
      int m = m0 + 64 * wrow + 16 * i + quad * 4 + rr;
      float* dst = out + (size_t)m * 1024 + colbase;
#pragma unroll
      for (int j = 0; j < 2; ++j) dst[j * 16 + lx] = acc[i][j][rr] + bb[j];
    }
  }
}

// ---------------------------------------------------------------------------
extern "C" void kernel_launch(void* const* d_in, const int* in_sizes, int n_in,
                              void* d_out, int out_size, void* d_ws, size_t ws_size,
                              hipStream_t stream) {
  (void)in_sizes; (void)n_in; (void)out_size; (void)ws_size;
  const float* x   = (const float*)d_in[0];
  const float* Qb  = (const float*)d_in[1];
  const float* Wq  = (const float*)d_in[2];
  const float* bq  = (const float*)d_in[3];
  const float* Wk  = (const float*)d_in[4];
  const float* bk  = (const float*)d_in[5];
  const float* Wv  = (const float*)d_in[6];
  const float* bv  = (const float*)d_in[7];
  const float* qls = (const float*)d_in[8];
  const float* kls = (const float*)d_in[9];
  const float* Ra  = (const float*)d_in[10];
  const float* Wo  = (const float*)d_in[11];
  const float* bo  = (const float*)d_in[12];
  float* out = (float*)d_out;

  char* ws = (char*)d_ws;
  unsigned short* xb    = (unsigned short*)(ws + 0);          //  8 MB  [4096][1024]
  unsigned short* wqkvt = (unsigned short*)(ws + 8388608);    //  6 MB  [3072][1024]
  unsigned short* wot   = (unsigned short*)(ws + 14680064);   //  2 MB  [1024][1024]
  unsigned short* qb    = (unsigned short*)(ws + 16777216);   //  8 MB  [b][h][s][hd]
  unsigned short* kb    = (unsigned short*)(ws + 25165824);   //  8 MB  [b][h][s][hd]
  unsigned short* vtb   = (unsigned short*)(ws + 33554432);   //  8 MB  [b][h][hd][s]
  unsigned short* ctxb  = (unsigned short*)(ws + 41943040);   //  8 MB  [b][s][h][hd]
  unsigned short* biasb = (unsigned short*)(ws + 50331648);   // 134 MB [h][q][k]
  // natural-layout V scratch: aliases ctxb (dead until k_attn writes it;
  // vnat is fully consumed by k_vt before k_attn runs)
  unsigned short* vnat  = ctxb;

  k_cvt_x<<<4096, 256, 0, stream>>>(x, xb);
  k_transpose<<<dim3(32, 32, 4), dim3(32, 8), 0, stream>>>(Wq, Wk, Wv, Wo, wqkvt, wot);
  k_bias<<<2048, 256, 0, stream>>>(Qb, Ra, biasb);
  k_qkv<<<dim3(24, 32), 256, 0, stream>>>(xb, wqkvt, bq, bk, bv, qls, kls, qb, kb, vnat);
  k_vt<<<dim3(32, 32), 256, 0, stream>>>(vnat, vtb);
  k_attn<<<dim3(32, 16, 2), 256, 0, stream>>>(qb, kb, vtb, biasb, ctxb);
  k_out<<<dim3(16, 32), 256, 0, stream>>>(ctxb, wot, bo, out);
}

// Round 6
// 414.678 us; speedup vs baseline: 1.0638x; 1.0638x over previous
//
#include <hip/hip_runtime.h>

typedef float f32x4 __attribute__((ext_vector_type(4)));
typedef __bf16 bf16x8 __attribute__((ext_vector_type(8)));
typedef unsigned short u16x8 __attribute__((ext_vector_type(8)));
typedef unsigned short u16x4 __attribute__((ext_vector_type(4)));

#define AS1 __attribute__((address_space(1)))
#define AS3 __attribute__((address_space(3)))

static __device__ __forceinline__ void gll16(const void* g, void* l) {
  // async global->LDS DMA, 16B/lane; LDS dest = wave-uniform base + lane*16
  __builtin_amdgcn_global_load_lds((const AS1 void*)g, (AS3 void*)l, 16, 0, 0);
}

static __device__ __forceinline__ float bf2f(unsigned short u) {
  unsigned int x = ((unsigned int)u) << 16;
  float f; __builtin_memcpy(&f, &x, 4); return f;
}
// native RNE f32->bf16
static __device__ __forceinline__ unsigned short f2bf(float f) {
  __bf16 h = (__bf16)f;
  unsigned short u; __builtin_memcpy(&u, &h, 2); return u;
}

#define LOG2E 1.4426950408889634f
// fold 1/sqrt(HD)=0.125 and log2(e) into stored q
#define QSCALE (0.125f * LOG2E)

// ---------------------------------------------------------------------------
// Kernel: convert x fp32 -> bf16 (elementwise).  4096x1024
// ---------------------------------------------------------------------------
__global__ __launch_bounds__(256) void k_cvt_x(const float* __restrict__ x,
                                               unsigned short* __restrict__ xb) {
  int i = (blockIdx.x * 256 + threadIdx.x) * 4;
  float4 v = *(const float4*)(x + i);
  u16x4 o; o.x = f2bf(v.x); o.y = f2bf(v.y); o.z = f2bf(v.z); o.w = f2bf(v.w);
  *(u16x4*)(xb + i) = o;
}

// ---------------------------------------------------------------------------
// Kernel: transpose 1024x1024 fp32 -> bf16 [n][k].  z: 0=Wq 1=Wk 2=Wv 3=Wo
// ---------------------------------------------------------------------------
__global__ __launch_bounds__(256) void k_transpose(const float* __restrict__ w0,
                                                   const float* __restrict__ w1,
                                                   const float* __restrict__ w2,
                                                   const float* __restrict__ w3,
                                                   unsigned short* __restrict__ dqkv,
                                                   unsigned short* __restrict__ dwo) {
  __shared__ float tile[32][33];
  int z = blockIdx.z;
  const float* src = (z == 0) ? w0 : (z == 1) ? w1 : (z == 2) ? w2 : w3;
  unsigned short* dst = (z < 3) ? (dqkv + (size_t)z * 1024 * 1024) : dwo;
  int tx = threadIdx.x, ty = threadIdx.y;
  int x0 = blockIdx.x * 32, y0 = blockIdx.y * 32;
#pragma unroll
  for (int i = 0; i < 4; ++i)
    tile[ty + 8 * i][tx] = src[(size_t)(y0 + ty + 8 * i) * 1024 + x0 + tx];
  __syncthreads();
#pragma unroll
  for (int i = 0; i < 4; ++i)
    dst[(size_t)(x0 + ty + 8 * i) * 1024 + y0 + tx] = f2bf(tile[tx][ty + 8 * i]);
}

// ---------------------------------------------------------------------------
// Kernel: bias in MFMA-FRAGMENT-TILED layout (bf16).
//   value (h,q,k) -> tile(h, qg=q>>4, kt=k>>6),
//   lane = ((q&15)>>2)*16 + (k&15),  idx = ((k>>4)&3)*4 + (q&3)
//   addr = (((h*128+qg)*32+kt)*64 + lane)*16 + idx    [u16 units]
// k_attn's per-wave-iter bias fragment becomes 2x u16x8 fully-coalesced loads
// (1KB contiguous per wave) instead of 16 scalar 2B loads touching 4 lines
// each (~2x over-fetch on the 134MB bias stream).
// grid (32 kt, 128 qg), 256 threads = 64 lanes x 4 h-groups.
// Reads of Qb coalesced (adjacent lanes -> adjacent 32B chunks); the 4
// h-group waves re-read the same Qb tile but hit L1 (same CU).
// ---------------------------------------------------------------------------
__global__ __launch_bounds__(256) void k_bias(const float* __restrict__ Qb,
                                              const float* __restrict__ R,
                                              unsigned short* __restrict__ bias) {
  __shared__ float Rs[8][16];
  int t = threadIdx.x;
  if (t < 128) Rs[t >> 4][t & 15] = R[t] * LOG2E;
  __syncthreads();
  const int lane = t & 63, hg = t >> 6;          // hg uniform per wave
  const int quad = lane >> 4, lx = lane & 15;
  const int kt = blockIdx.x;                      // 0..31  (64 k each)
  const int qg = blockIdx.y;                      // 0..127 (16 q each)

  u16x8 out[4][2];                                // [h-local][lo/hi]
#pragma unroll
  for (int j = 0; j < 4; ++j) {
#pragma unroll
    for (int rr = 0; rr < 4; ++rr) {
      const int q = qg * 16 + quad * 4 + rr;
      const int k = kt * 64 + j * 16 + lx;
      const float* ap = Qb + ((size_t)q * 2048 + k) * 8;
      float4 c0 = *(const float4*)ap;
      float4 c1 = *(const float4*)(ap + 4);
#pragma unroll
      for (int hh = 0; hh < 4; ++hh) {
        const int h = hg * 4 + hh;
        float s = c0.x * Rs[0][h] + c0.y * Rs[1][h] + c0.z * Rs[2][h] + c0.w * Rs[3][h]
                + c1.x * Rs[4][h] + c1.y * Rs[5][h] + c1.z * Rs[6][h] + c1.w * Rs[7][h];
        const int v = j * 4 + rr;                 // compile-time (unrolled)
        out[hh][v >> 3][v & 7] = f2bf(s);
      }
    }
  }
#pragma unroll
  for (int hh = 0; hh < 4; ++hh) {
    const int h = hg * 4 + hh;
    unsigned short* dst = bias + ((((size_t)h * 128 + qg) * 32 + kt) * 64 + lane) * 16;
    *(u16x8*)dst = out[hh][0];
    *(u16x8*)(dst + 8) = out[hh][1];
  }
}

// ---------------------------------------------------------------------------
// Kernel: QKV GEMM  C[4096][3072] = x_bf16[4096][1024] @ Wqkv_t^T  + fused QK-LN
// 2-phase double-buffered staging, one barrier per K-step.  (R3 config:
// V written directly transposed; k_vt detour measured as a net regression.)
// ---------------------------------------------------------------------------
__global__ __launch_bounds__(256) void k_qkv(const unsigned short* __restrict__ xb,
                                             const unsigned short* __restrict__ wt,
                                             const float* __restrict__ bq,
                                             const float* __restrict__ bk,
                                             const float* __restrict__ bv,
                                             const float* __restrict__ qls,
                                             const float* __restrict__ kls,
                                             unsigned short* __restrict__ qo,
                                             unsigned short* __restrict__ kqo,
                                             unsigned short* __restrict__ vo) {
  __shared__ __align__(16) unsigned short As[8192];  // 2 x [128 m][32 k]
  __shared__ __align__(16) unsigned short Bs[8192];  // 2 x [128 n][32 k]
  const int tid = threadIdx.x;
  const int w = tid >> 6, lane = tid & 63, quad = lane >> 4, lx = lane & 15;
  const int m0 = blockIdx.y * 128, n0 = blockIdx.x * 128;
  const int wrow = w >> 1, wcol = w & 1;

  f32x4 acc[4][4];
#pragma unroll
  for (int i = 0; i < 4; ++i)
#pragma unroll
    for (int j = 0; j < 4; ++j) acc[i][j] = (f32x4){0.f, 0.f, 0.f, 0.f};

  const unsigned short* ga = xb + (size_t)(m0 + 32 * w + (lane >> 2)) * 1024 + (lane & 3) * 8;
  const unsigned short* gb = wt + (size_t)(n0 + 32 * w + (lane >> 2)) * 1024 + (lane & 3) * 8;

  gll16(ga, As + w * 1024);
  gll16(ga + 16 * 1024, As + w * 1024 + 512);
  gll16(gb, Bs + w * 1024);
  gll16(gb + 16 * 1024, Bs + w * 1024 + 512);
  __syncthreads();

  for (int kt = 0; kt < 32; ++kt) {
    const int cur = kt & 1;
    if (kt < 31) {
      const int kofs = (kt + 1) * 32;
      unsigned short* lan = As + (cur ^ 1) * 4096 + w * 1024;
      unsigned short* lbn = Bs + (cur ^ 1) * 4096 + w * 1024;
      gll16(ga + kofs, lan);
      gll16(ga + kofs + 16 * 1024, lan + 512);
      gll16(gb + kofs, lbn);
      gll16(gb + kofs + 16 * 1024, lbn + 512);
    }
    const unsigned short* ac = As + cur * 4096;
    const unsigned short* bc = Bs + cur * 4096;
    bf16x8 af[4], bfr[4];
#pragma unroll
    for (int i = 0; i < 4; ++i)
      af[i] = *(const bf16x8*)&ac[(64 * wrow + 16 * i + lx) * 32 + quad * 8];
#pragma unroll
    for (int j = 0; j < 4; ++j)
      bfr[j] = *(const bf16x8*)&bc[(64 * wcol + 16 * j + lx) * 32 + quad * 8];
    __builtin_amdgcn_s_setprio(1);
#pragma unroll
    for (int i = 0; i < 4; ++i)
#pragma unroll
      for (int j = 0; j < 4; ++j)
        acc[i][j] = __builtin_amdgcn_mfma_f32_16x16x32_bf16(af[i], bfr[j], acc[i][j], 0, 0, 0);
    __builtin_amdgcn_s_setprio(0);
    __syncthreads();
  }

  const int colbase = n0 + 64 * wcol;
  const int region = colbase >> 10;         // 0=q 1=k 2=v
  const int h = (colbase & 1023) >> 6;
  const float* pbp = (region == 0) ? bq : (region == 1) ? bk : bv;
  float pb[4];
#pragma unroll
  for (int j = 0; j < 4; ++j) pb[j] = pbp[h * 64 + j * 16 + lx];

  if (region == 2) {
#pragma unroll
    for (int i = 0; i < 4; ++i) {
#pragma unroll
      for (int rr = 0; rr < 4; ++rr) {
        int m = m0 + 64 * wrow + 16 * i + quad * 4 + rr;
        int b = m >> 11, s = m & 2047;
        unsigned short* dst = vo + ((size_t)b * 16 + h) * 64 * 2048 + s;
#pragma unroll
        for (int j = 0; j < 4; ++j)
          dst[(size_t)(j * 16 + lx) * 2048] = f2bf(acc[i][j][rr] + pb[j]);
      }
    }
  } else {
    const float fac = region ? 1.0f : QSCALE;
    float scl[4];
    const float* lsp = region ? kls : qls;
#pragma unroll
    for (int j = 0; j < 4; ++j) scl[j] = lsp[j * 16 + lx] * fac;
    unsigned short* base = region ? kqo : qo;
#pragma unroll
    for (int i = 0; i < 4; ++i) {
#pragma unroll
      for (int rr = 0; rr < 4; ++rr) {
        int m = m0 + 64 * wrow + 16 * i + quad * 4 + rr;
        int b = m >> 11, s = m & 2047;
        float v0 = acc[i][0][rr] + pb[0];
        float v1 = acc[i][1][rr] + pb[1];
        float v2 = acc[i][2][rr] + pb[2];
        float v3 = acc[i][3][rr] + pb[3];
        float s1 = v0 + v1 + v2 + v3;
        float s2 = v0 * v0 + v1 * v1 + v2 * v2 + v3 * v3;
#pragma unroll
        for (int d = 1; d < 16; d <<= 1) {
          s1 += __shfl_xor(s1, d, 64);
          s2 += __shfl_xor(s2, d, 64);
        }
        float mu = s1 * 0.015625f;
        float var = s2 * 0.015625f - mu * mu;
        float ri = __builtin_amdgcn_rsqf(var + 1e-6f);
        unsigned short* dst = base + (((size_t)b * 16 + h) * 2048 + s) * 64;
        dst[0 * 16 + lx] = f2bf((v0 - mu) * ri * scl[0]);
        dst[1 * 16 + lx] = f2bf((v1 - mu) * ri * scl[1]);
        dst[2 * 16 + lx] = f2bf((v2 - mu) * ri * scl[2]);
        dst[3 * 16 + lx] = f2bf((v3 - mu) * ri * scl[3]);
      }
    }
  }
}

// ---------------------------------------------------------------------------
// Kernel: flash attention, fixed-reference softmax.  Round-1/3 structure
// (best measured 103-104us, 98K bank conflicts) with bias loads switched to
// the fragment-tiled layout: 2x u16x8 per iter (fully coalesced, zero
// over-fetch) instead of 16 scalar loads touching 4 cachelines each.
// ---------------------------------------------------------------------------
__global__ __launch_bounds__(256) void k_attn(const unsigned short* __restrict__ qp,
                                              const unsigned short* __restrict__ kp,
                                              const unsigned short* __restrict__ vp,
                                              const unsigned short* __restrict__ bp,
                                              unsigned short* __restrict__ ctx) {
  __shared__ __align__(16) unsigned short QPs[4096]; // Q stage, then per-wave P (swizzled)
  __shared__ __align__(16) unsigned short Ks[8192];  // 2 x [64 key][64 hd] swizzled chunks
  __shared__ __align__(16) unsigned short Vs[8192];  // 2 x [64 hd][64 key] swizzled chunks
  const int tid = threadIdx.x;
  const int w = tid >> 6, lane = tid & 63, quad = lane >> 4, lx = lane & 15;
  const int lx7 = lane & 7;
  const int qt = blockIdx.x, h = blockIdx.y, b = blockIdx.z;
  const int q0 = qt * 64;
  const size_t bh = (size_t)b * 16 + h;

  // stage Q (contiguous 8KB, natural layout; consumed into regs after barrier)
  const unsigned short* qg = qp + (bh * 2048 + q0) * 64;
  gll16(qg + w * 512 + lane * 8, QPs + w * 512);
  gll16(qg + 2048 + w * 512 + lane * 8, QPs + 2048 + w * 512);

  const unsigned short* kg = kp + bh * 2048 * 64;
  const unsigned short* vg = vp + bh * 64 * 2048;
  // fragment-tiled bias: tile base for (h, qg = q0/16 + w), stepped by kt*1024
  const unsigned short* bgt = bp + ((((size_t)h * 128 + (q0 >> 4) + w) * 32) * 64 + lane) * 16;

  // DMA source for swizzled staging: lane covers (row=16w+(lane>>3)(+8), chunk=lane&7)
  const int rA = 16 * w + (lane >> 3);
  const int cA = (lane & 7) ^ (rA & 7);          // logical chunk fetched into phys slot lane&7
  const unsigned short* kgA = kg + (size_t)rA * 64 + cA * 8;        // + k0*64 per tile
  const unsigned short* kgB = kg + (size_t)(rA + 8) * 64 + cA * 8;
  const unsigned short* vgA = vg + (size_t)rA * 2048 + cA * 8;      // + k0 per tile
  const unsigned short* vgB = vg + (size_t)(rA + 8) * 2048 + cA * 8;

  // prologue: stage kt=0 K/V into buffer 0, load kt=0 bias fragments
  gll16(kgA, Ks + w * 1024);
  gll16(kgB, Ks + w * 1024 + 512);
  gll16(vgA, Vs + w * 1024);
  gll16(vgB, Vs + w * 1024 + 512);
  u16x8 bu_lo = *(const u16x8*)(bgt);
  u16x8 bu_hi = *(const u16x8*)(bgt + 8);
  u16x8 bun_lo = bu_lo, bun_hi = bu_hi;

  __syncthreads();

  bf16x8 qf[2];
#pragma unroll
  for (int hh = 0; hh < 2; ++hh)
    qf[hh] = *(const bf16x8*)&QPs[(16 * w + lx) * 64 + hh * 32 + quad * 8];

  float l_run[4] = {0.f, 0.f, 0.f, 0.f};
  f32x4 acco[4];
#pragma unroll
  for (int j = 0; j < 4; ++j) acco[j] = (f32x4){0.f, 0.f, 0.f, 0.f};

  for (int kt = 0; kt < 32; ++kt) {
    const int cur = kt & 1;
    const unsigned short* kc = Ks + cur * 4096;
    const unsigned short* vc = Vs + cur * 4096;
    // issue next tile's DMA + bias prefetch before computing current tile
    if (kt < 31) {
      const size_t k1 = (size_t)(kt + 1) * 64;
      unsigned short* kn = Ks + (cur ^ 1) * 4096 + w * 1024;
      unsigned short* vn = Vs + (cur ^ 1) * 4096 + w * 1024;
      gll16(kgA + k1 * 64, kn);
      gll16(kgB + k1 * 64, kn + 512);
      gll16(vgA + k1, vn);
      gll16(vgB + k1, vn + 512);
      bun_lo = *(const u16x8*)(bgt + (size_t)(kt + 1) * 1024);
      bun_hi = *(const u16x8*)(bgt + (size_t)(kt + 1) * 1024 + 8);
    }

    // accs[j][rr] init from fragment-tiled bias: idx = j*4+rr
    f32x4 accs[4];
#pragma unroll
    for (int j = 0; j < 4; ++j)
#pragma unroll
      for (int rr = 0; rr < 4; ++rr)
        accs[j][rr] = bf2f((j < 2) ? bu_lo[(j & 1) * 4 + rr] : bu_hi[(j & 1) * 4 + rr]);
    __builtin_amdgcn_s_setprio(1);
#pragma unroll
    for (int j = 0; j < 4; ++j) {
#pragma unroll
      for (int hh = 0; hh < 2; ++hh) {
        bf16x8 kf = *(const bf16x8*)&kc[(j * 16 + lx) * 64 + ((hh * 4 + quad) ^ lx7) * 8];
        accs[j] = __builtin_amdgcn_mfma_f32_16x16x32_bf16(qf[hh], kf, accs[j], 0, 0, 0);
      }
    }
    __builtin_amdgcn_s_setprio(0);

    // fixed-reference softmax: p = exp2(score), per-lane partial l, no max
#pragma unroll
    for (int rr = 0; rr < 4; ++rr) {
      float p0 = __builtin_amdgcn_exp2f(accs[0][rr]);
      float p1 = __builtin_amdgcn_exp2f(accs[1][rr]);
      float p2 = __builtin_amdgcn_exp2f(accs[2][rr]);
      float p3 = __builtin_amdgcn_exp2f(accs[3][rr]);
      l_run[rr] += (p0 + p1) + (p2 + p3);
      // P write: q=quad*4+rr, k=lx+16j; phys chunk = (k>>3) ^ (q&7)
      const int q = quad * 4 + rr;
      const int swz = q & 7;
      const int ch = lx >> 3;
      unsigned short* pw = QPs + w * 1024 + q * 64 + (lx & 7);
      pw[((ch ^ swz) << 3)]       = f2bf(p0);
      pw[(((ch + 2) ^ swz) << 3)] = f2bf(p1);
      pw[(((ch + 4) ^ swz) << 3)] = f2bf(p2);
      pw[(((ch + 6) ^ swz) << 3)] = f2bf(p3);
    }
    __asm__ volatile("s_waitcnt lgkmcnt(0)" ::: "memory");
    bf16x8 pf[2];
#pragma unroll
    for (int kh = 0; kh < 2; ++kh)
      pf[kh] = *(const bf16x8*)&QPs[w * 1024 + lx * 64 + (((kh * 4 + quad) ^ (lx & 7)) << 3)];
    __builtin_amdgcn_s_setprio(1);
#pragma unroll
    for (int j = 0; j < 4; ++j) {
#pragma unroll
      for (int kh = 0; kh < 2; ++kh) {
        bf16x8 vf = *(const bf16x8*)&vc[(j * 16 + lx) * 64 + ((kh * 4 + quad) ^ lx7) * 8];
        acco[j] = __builtin_amdgcn_mfma_f32_16x16x32_bf16(pf[kh], vf, acco[j], 0, 0, 0);
      }
    }
    __builtin_amdgcn_s_setprio(0);
    __syncthreads();   // waves done with buf[cur]; DMA into buf[cur^1] drained here
    bu_lo = bun_lo;
    bu_hi = bun_hi;
  }

  // epilogue: one cross-lane l reduction, O /= l, write ctx[b][s][h][hd] bf16
#pragma unroll
  for (int rr = 0; rr < 4; ++rr) {
    float l = l_run[rr];
#pragma unroll
    for (int d = 1; d < 16; d <<= 1) l += __shfl_xor(l, d, 64);
    float rl = __builtin_amdgcn_rcpf(l);
    int s = q0 + 16 * w + quad * 4 + rr;
    unsigned short* dst = ctx + (((size_t)b * 2048 + s) * 16 + h) * 64;
#pragma unroll
    for (int j = 0; j < 4; ++j) dst[j * 16 + lx] = f2bf(acco[j][rr] * rl);
  }
}

// ---------------------------------------------------------------------------
// Kernel: output GEMM  out[4096][1024] = ctx[4096][1024] @ Wo_t^T + bo  (fp32)
// 128x64 tiles -> 512 blocks (2 blocks/CU).  24KB LDS double-buffered.
// ---------------------------------------------------------------------------
__global__ __launch_bounds__(256) void k_out(const unsigned short* __restrict__ cx,
                                             const unsigned short* __restrict__ wt,
                                             const float* __restrict__ bo,
                                             float* __restrict__ out) {
  __shared__ __align__(16) unsigned short As[8192];  // 2 x [128 m][32 k]
  __shared__ __align__(16) unsigned short Bs[4096];  // 2 x [ 64 n][32 k]
  const int tid = threadIdx.x;
  const int w = tid >> 6, lane = tid & 63, quad = lane >> 4, lx = lane & 15;
  const int m0 = blockIdx.y * 128, n0 = blockIdx.x * 64;
  const int wrow = w >> 1, wcol = w & 1;

  f32x4 acc[4][2];
#pragma unroll
  for (int i = 0; i < 4; ++i)
#pragma unroll
    for (int j = 0; j < 2; ++j) acc[i][j] = (f32x4){0.f, 0.f, 0.f, 0.f};

  const unsigned short* ga = cx + (size_t)(m0 + 32 * w + (lane >> 2)) * 1024 + (lane & 3) * 8;
  const unsigned short* gb = wt + (size_t)(n0 + 16 * w + (lane >> 2)) * 1024 + (lane & 3) * 8;

  gll16(ga, As + w * 1024);
  gll16(ga + 16 * 1024, As + w * 1024 + 512);
  gll16(gb, Bs + w * 512);
  __syncthreads();

  for (int kt = 0; kt < 32; ++kt) {
    const int cur = kt & 1;
    if (kt < 31) {
      const int kofs = (kt + 1) * 32;
      unsigned short* lan = As + (cur ^ 1) * 4096 + w * 1024;
      gll16(ga + kofs, lan);
      gll16(ga + kofs + 16 * 1024, lan + 512);
      gll16(gb + kofs, Bs + (cur ^ 1) * 2048 + w * 512);
    }
    const unsigned short* ac = As + cur * 4096;
    const unsigned short* bc = Bs + cur * 2048;
    bf16x8 af[4], bfr[2];
#pragma unroll
    for (int i = 0; i < 4; ++i)
      af[i] = *(const bf16x8*)&ac[(64 * wrow + 16 * i + lx) * 32 + quad * 8];
#pragma unroll
    for (int j = 0; j < 2; ++j)
      bfr[j] = *(const bf16x8*)&bc[(32 * wcol + 16 * j + lx) * 32 + quad * 8];
    __builtin_amdgcn_s_setprio(1);
#pragma unroll
    for (int i = 0; i < 4; ++i)
#pragma unroll
      for (int j = 0; j < 2; ++j)
        acc[i][j] = __builtin_amdgcn_mfma_f32_16x16x32_bf16(af[i], bfr[j], acc[i][j], 0, 0, 0);
    __builtin_amdgcn_s_setprio(0);
    __syncthreads();
  }

  const int colbase = n0 + 32 * wcol;
  float bb[2];
#pragma unroll
  for (int j = 0; j < 2; ++j) bb[j] = bo[colbase + j * 16 + lx];
#pragma unroll
  for (int i = 0; i < 4; ++i) {
#pragma unroll
    for (int rr = 0; rr < 4; ++rr) {
      int m = m0 + 64 * wrow + 16 * i + quad * 4 + rr;
      float* dst = out + (size_t)m * 1024 + colbase;
#pragma unroll
      for (int j = 0; j < 2; ++j) dst[j * 16 + lx] = acc[i][j][rr] + bb[j];
    }
  }
}

// ---------------------------------------------------------------------------
extern "C" void kernel_launch(void* const* d_in, const int* in_sizes, int n_in,
                              void* d_out, int out_size, void* d_ws, size_t ws_size,
                              hipStream_t stream) {
  (void)in_sizes; (void)n_in; (void)out_size; (void)ws_size;
  const float* x   = (const float*)d_in[0];
  const float* Qb  = (const float*)d_in[1];
  const float* Wq  = (const float*)d_in[2];
  const float* bq  = (const float*)d_in[3];
  const float* Wk  = (const float*)d_in[4];
  const float* bk  = (const float*)d_in[5];
  const float* Wv  = (const float*)d_in[6];
  const float* bv  = (const float*)d_in[7];
  const float* qls = (const float*)d_in[8];
  const float* kls = (const float*)d_in[9];
  const float* Ra  = (const float*)d_in[10];
  const float* Wo  = (const float*)d_in[11];
  const float* bo  = (const float*)d_in[12];
  float* out = (float*)d_out;

  char* ws = (char*)d_ws;
  unsigned short* xb    = (unsigned short*)(ws + 0);          //  8 MB  [4096][1024]
  unsigned short* wqkvt = (unsigned short*)(ws + 8388608);    //  6 MB  [3072][1024]
  unsigned short* wot   = (unsigned short*)(ws + 14680064);   //  2 MB  [1024][1024]
  unsigned short* qb    = (unsigned short*)(ws + 16777216);   //  8 MB  [b][h][s][hd]
  unsigned short* kb    = (unsigned short*)(ws + 25165824);   //  8 MB  [b][h][s][hd]
  unsigned short* vtb   = (unsigned short*)(ws + 33554432);   //  8 MB  [b][h][hd][s]
  unsigned short* ctxb  = (unsigned short*)(ws + 41943040);   //  8 MB  [b][s][h][hd]
  unsigned short* biasb = (unsigned short*)(ws + 50331648);   // 134 MB fragment-tiled

  k_cvt_x<<<4096, 256, 0, stream>>>(x, xb);
  k_transpose<<<dim3(32, 32, 4), dim3(32, 8), 0, stream>>>(Wq, Wk, Wv, Wo, wqkvt, wot);
  k_bias<<<dim3(32, 128), 256, 0, stream>>>(Qb, Ra, biasb);
  k_qkv<<<dim3(24, 32), 256, 0, stream>>>(xb, wqkvt, bq, bk, bv, qls, kls, qb, kb, vtb);
  k_attn<<<dim3(32, 16, 2), 256, 0, stream>>>(qb, kb, vtb, biasb, ctxb);
  k_out<<<dim3(16, 32), 256, 0, stream>>>(ctxb, wot, bo, out);
}

// Round 7
// 405.321 us; speedup vs baseline: 1.0883x; 1.0231x over previous
//
#include <hip/hip_runtime.h>

typedef float f32x4 __attribute__((ext_vector_type(4)));
typedef __bf16 bf16x8 __attribute__((ext_vector_type(8)));
typedef unsigned short u16x8 __attribute__((ext_vector_type(8)));
typedef unsigned short u16x4 __attribute__((ext_vector_type(4)));

#define AS1 __attribute__((address_space(1)))
#define AS3 __attribute__((address_space(3)))

static __device__ __forceinline__ void gll16(const void* g, void* l) {
  // async global->LDS DMA, 16B/lane; LDS dest = wave-uniform base + lane*16
  __builtin_amdgcn_global_load_lds((const AS1 void*)g, (AS3 void*)l, 16, 0, 0);
}

static __device__ __forceinline__ float bf2f(unsigned short u) {
  unsigned int x = ((unsigned int)u) << 16;
  float f; __builtin_memcpy(&f, &x, 4); return f;
}
// native RNE f32->bf16
static __device__ __forceinline__ unsigned short f2bf(float f) {
  __bf16 h = (__bf16)f;
  unsigned short u; __builtin_memcpy(&u, &h, 2); return u;
}

#define LOG2E 1.4426950408889634f
// fold 1/sqrt(HD)=0.125 and log2(e) into stored q
#define QSCALE (0.125f * LOG2E)

// ---------------------------------------------------------------------------
// Kernel: fused preprocessing (independent work, one dispatch):
//   blocks 0..4095    : x fp32 -> bf16 (4096x1024)
//   blocks 4096..8191 : transpose 1024x1024 fp32 -> bf16 [n][k], z=0..3
// ---------------------------------------------------------------------------
__global__ __launch_bounds__(256) void k_pre(const float* __restrict__ x,
                                             const float* __restrict__ w0,
                                             const float* __restrict__ w1,
                                             const float* __restrict__ w2,
                                             const float* __restrict__ w3,
                                             unsigned short* __restrict__ xb,
                                             unsigned short* __restrict__ dqkv,
                                             unsigned short* __restrict__ dwo) {
  __shared__ float tile[32][33];
  const int bid = blockIdx.x;
  const int t = threadIdx.x;
  if (bid < 4096) {
    int i = (bid * 256 + t) * 4;
    float4 v = *(const float4*)(x + i);
    u16x4 o; o.x = f2bf(v.x); o.y = f2bf(v.y); o.z = f2bf(v.z); o.w = f2bf(v.w);
    *(u16x4*)(xb + i) = o;
  } else {
    const int b2 = bid - 4096;
    const int z = b2 >> 10;            // 0..3
    const int rem = b2 & 1023;
    const int by = rem >> 5, bx = rem & 31;
    const float* src = (z == 0) ? w0 : (z == 1) ? w1 : (z == 2) ? w2 : w3;
    unsigned short* dst = (z < 3) ? (dqkv + (size_t)z * 1024 * 1024) : dwo;
    const int tx = t & 31, ty = t >> 5;
    const int x0 = bx * 32, y0 = by * 32;
#pragma unroll
    for (int i = 0; i < 4; ++i)
      tile[ty + 8 * i][tx] = src[(size_t)(y0 + ty + 8 * i) * 1024 + x0 + tx];
    __syncthreads();
#pragma unroll
    for (int i = 0; i < 4; ++i)
      dst[(size_t)(x0 + ty + 8 * i) * 1024 + y0 + tx] = f2bf(tile[tx][ty + 8 * i]);
  }
}

// ---------------------------------------------------------------------------
// Kernel: fused QKV GEMM + bias precompute (independent work, one dispatch;
// the ~50us bias memory stream hides under the MFMA-bound GEMM).
//   blocks 0..767    : QKV GEMM 128x128 tiles (bx=n-block%24? see decode)
//   blocks 768..4863 : bias fragment-tiled precompute
// GEMM blocks first in the grid -> dispatched first (critical path).
//
// GEMM: C[4096][3072] = x_bf16 @ Wqkv_t^T + fused QK-LN, 2-phase dbuf
// staging, one barrier per K-step.  V written directly transposed.
//
// bias: MFMA-FRAGMENT-TILED layout (bf16):
//   value (h,q,k) -> tile(h, qg=q>>4, kt=k>>6),
//   lane = ((q&15)>>2)*16 + (k&15),  idx = ((k>>4)&3)*4 + (q&3)
//   addr = (((h*128+qg)*32+kt)*64 + lane)*16 + idx    [u16 units]
// ---------------------------------------------------------------------------
__global__ __launch_bounds__(256) void k_qkv_bias(
    const unsigned short* __restrict__ xb,
    const unsigned short* __restrict__ wt,
    const float* __restrict__ bq,
    const float* __restrict__ bk,
    const float* __restrict__ bv,
    const float* __restrict__ qls,
    const float* __restrict__ kls,
    unsigned short* __restrict__ qo,
    unsigned short* __restrict__ kqo,
    unsigned short* __restrict__ vo,
    const float* __restrict__ Qb,
    const float* __restrict__ R,
    unsigned short* __restrict__ bias) {
  __shared__ __align__(16) unsigned short As[8192];  // 2 x [128 m][32 k]
  __shared__ __align__(16) unsigned short Bs[8192];  // 2 x [128 n][32 k]
  __shared__ float Rs[8][16];
  const int bid = blockIdx.x;
  const int tid = threadIdx.x;

  if (bid >= 768) {
    // ---------------- bias path ----------------
    const int bb = bid - 768;
    const int kt = bb & 31;                       // 0..31  (64 k each)
    const int qg = bb >> 5;                       // 0..127 (16 q each)
    if (tid < 128) Rs[tid >> 4][tid & 15] = R[tid] * LOG2E;
    __syncthreads();
    const int lane = tid & 63, hg = tid >> 6;     // hg uniform per wave
    const int quad = lane >> 4, lx = lane & 15;

    u16x8 out[4][2];                              // [h-local][lo/hi]
#pragma unroll
    for (int j = 0; j < 4; ++j) {
#pragma unroll
      for (int rr = 0; rr < 4; ++rr) {
        const int q = qg * 16 + quad * 4 + rr;
        const int k = kt * 64 + j * 16 + lx;
        const float* ap = Qb + ((size_t)q * 2048 + k) * 8;
        float4 c0 = *(const float4*)ap;
        float4 c1 = *(const float4*)(ap + 4);
#pragma unroll
        for (int hh = 0; hh < 4; ++hh) {
          const int h = hg * 4 + hh;
          float s = c0.x * Rs[0][h] + c0.y * Rs[1][h] + c0.z * Rs[2][h] + c0.w * Rs[3][h]
                  + c1.x * Rs[4][h] + c1.y * Rs[5][h] + c1.z * Rs[6][h] + c1.w * Rs[7][h];
          const int v = j * 4 + rr;               // compile-time (unrolled)
          out[hh][v >> 3][v & 7] = f2bf(s);
        }
      }
    }
#pragma unroll
    for (int hh = 0; hh < 4; ++hh) {
      const int h = hg * 4 + hh;
      unsigned short* dst = bias + ((((size_t)h * 128 + qg) * 32 + kt) * 64 + lane) * 16;
      *(u16x8*)dst = out[hh][0];
      *(u16x8*)(dst + 8) = out[hh][1];
    }
    return;
  }

  // ---------------- QKV GEMM path ----------------
  const int w = tid >> 6, lane = tid & 63, quad = lane >> 4, lx = lane & 15;
  const int m0 = (bid / 24) * 128, n0 = (bid % 24) * 128;
  const int wrow = w >> 1, wcol = w & 1;

  f32x4 acc[4][4];
#pragma unroll
  for (int i = 0; i < 4; ++i)
#pragma unroll
    for (int j = 0; j < 4; ++j) acc[i][j] = (f32x4){0.f, 0.f, 0.f, 0.f};

  const unsigned short* ga = xb + (size_t)(m0 + 32 * w + (lane >> 2)) * 1024 + (lane & 3) * 8;
  const unsigned short* gb = wt + (size_t)(n0 + 32 * w + (lane >> 2)) * 1024 + (lane & 3) * 8;

  gll16(ga, As + w * 1024);
  gll16(ga + 16 * 1024, As + w * 1024 + 512);
  gll16(gb, Bs + w * 1024);
  gll16(gb + 16 * 1024, Bs + w * 1024 + 512);
  __syncthreads();

  for (int kt = 0; kt < 32; ++kt) {
    const int cur = kt & 1;
    if (kt < 31) {
      const int kofs = (kt + 1) * 32;
      unsigned short* lan = As + (cur ^ 1) * 4096 + w * 1024;
      unsigned short* lbn = Bs + (cur ^ 1) * 4096 + w * 1024;
      gll16(ga + kofs, lan);
      gll16(ga + kofs + 16 * 1024, lan + 512);
      gll16(gb + kofs, lbn);
      gll16(gb + kofs + 16 * 1024, lbn + 512);
    }
    const unsigned short* ac = As + cur * 4096;
    const unsigned short* bc = Bs + cur * 4096;
    bf16x8 af[4], bfr[4];
#pragma unroll
    for (int i = 0; i < 4; ++i)
      af[i] = *(const bf16x8*)&ac[(64 * wrow + 16 * i + lx) * 32 + quad * 8];
#pragma unroll
    for (int j = 0; j < 4; ++j)
      bfr[j] = *(const bf16x8*)&bc[(64 * wcol + 16 * j + lx) * 32 + quad * 8];
    __builtin_amdgcn_s_setprio(1);
#pragma unroll
    for (int i = 0; i < 4; ++i)
#pragma unroll
      for (int j = 0; j < 4; ++j)
        acc[i][j] = __builtin_amdgcn_mfma_f32_16x16x32_bf16(af[i], bfr[j], acc[i][j], 0, 0, 0);
    __builtin_amdgcn_s_setprio(0);
    __syncthreads();
  }

  const int colbase = n0 + 64 * wcol;
  const int region = colbase >> 10;         // 0=q 1=k 2=v
  const int h = (colbase & 1023) >> 6;
  const float* pbp = (region == 0) ? bq : (region == 1) ? bk : bv;
  float pb[4];
#pragma unroll
  for (int j = 0; j < 4; ++j) pb[j] = pbp[h * 64 + j * 16 + lx];

  if (region == 2) {
#pragma unroll
    for (int i = 0; i < 4; ++i) {
#pragma unroll
      for (int rr = 0; rr < 4; ++rr) {
        int m = m0 + 64 * wrow + 16 * i + quad * 4 + rr;
        int b = m >> 11, s = m & 2047;
        unsigned short* dst = vo + ((size_t)b * 16 + h) * 64 * 2048 + s;
#pragma unroll
        for (int j = 0; j < 4; ++j)
          dst[(size_t)(j * 16 + lx) * 2048] = f2bf(acc[i][j][rr] + pb[j]);
      }
    }
  } else {
    const float fac = region ? 1.0f : QSCALE;
    float scl[4];
    const float* lsp = region ? kls : qls;
#pragma unroll
    for (int j = 0; j < 4; ++j) scl[j] = lsp[j * 16 + lx] * fac;
    unsigned short* base = region ? kqo : qo;
#pragma unroll
    for (int i = 0; i < 4; ++i) {
#pragma unroll
      for (int rr = 0; rr < 4; ++rr) {
        int m = m0 + 64 * wrow + 16 * i + quad * 4 + rr;
        int b = m >> 11, s = m & 2047;
        float v0 = acc[i][0][rr] + pb[0];
        float v1 = acc[i][1][rr] + pb[1];
        float v2 = acc[i][2][rr] + pb[2];
        float v3 = acc[i][3][rr] + pb[3];
        float s1 = v0 + v1 + v2 + v3;
        float s2 = v0 * v0 + v1 * v1 + v2 * v2 + v3 * v3;
#pragma unroll
        for (int d = 1; d < 16; d <<= 1) {
          s1 += __shfl_xor(s1, d, 64);
          s2 += __shfl_xor(s2, d, 64);
        }
        float mu = s1 * 0.015625f;
        float var = s2 * 0.015625f - mu * mu;
        float ri = __builtin_amdgcn_rsqf(var + 1e-6f);
        unsigned short* dst = base + (((size_t)b * 16 + h) * 2048 + s) * 64;
        dst[0 * 16 + lx] = f2bf((v0 - mu) * ri * scl[0]);
        dst[1 * 16 + lx] = f2bf((v1 - mu) * ri * scl[1]);
        dst[2 * 16 + lx] = f2bf((v2 - mu) * ri * scl[2]);
        dst[3 * 16 + lx] = f2bf((v3 - mu) * ri * scl[3]);
      }
    }
  }
}

// ---------------------------------------------------------------------------
// Kernel: flash attention, fixed-reference softmax.  (Byte-identical to R6:
// 88us, FETCH 183MB, conflicts 98K.)  2-phase dbuf K/V staging; P overlaid
// on Q LDS with XOR chunk-swizzle; fragment-tiled bias (2x u16x8 per iter).
// ---------------------------------------------------------------------------
__global__ __launch_bounds__(256) void k_attn(const unsigned short* __restrict__ qp,
                                              const unsigned short* __restrict__ kp,
                                              const unsigned short* __restrict__ vp,
                                              const unsigned short* __restrict__ bp,
                                              unsigned short* __restrict__ ctx) {
  __shared__ __align__(16) unsigned short QPs[4096]; // Q stage, then per-wave P (swizzled)
  __shared__ __align__(16) unsigned short Ks[8192];  // 2 x [64 key][64 hd] swizzled chunks
  __shared__ __align__(16) unsigned short Vs[8192];  // 2 x [64 hd][64 key] swizzled chunks
  const int tid = threadIdx.x;
  const int w = tid >> 6, lane = tid & 63, quad = lane >> 4, lx = lane & 15;
  const int lx7 = lane & 7;
  const int qt = blockIdx.x, h = blockIdx.y, b = blockIdx.z;
  const int q0 = qt * 64;
  const size_t bh = (size_t)b * 16 + h;

  // stage Q (contiguous 8KB, natural layout; consumed into regs after barrier)
  const unsigned short* qg = qp + (bh * 2048 + q0) * 64;
  gll16(qg + w * 512 + lane * 8, QPs + w * 512);
  gll16(qg + 2048 + w * 512 + lane * 8, QPs + 2048 + w * 512);

  const unsigned short* kg = kp + bh * 2048 * 64;
  const unsigned short* vg = vp + bh * 64 * 2048;
  // fragment-tiled bias: tile base for (h, qg = q0/16 + w), stepped by kt*1024
  const unsigned short* bgt = bp + ((((size_t)h * 128 + (q0 >> 4) + w) * 32) * 64 + lane) * 16;

  // DMA source for swizzled staging: lane covers (row=16w+(lane>>3)(+8), chunk=lane&7)
  const int rA = 16 * w + (lane >> 3);
  const int cA = (lane & 7) ^ (rA & 7);          // logical chunk fetched into phys slot lane&7
  const unsigned short* kgA = kg + (size_t)rA * 64 + cA * 8;        // + k0*64 per tile
  const unsigned short* kgB = kg + (size_t)(rA + 8) * 64 + cA * 8;
  const unsigned short* vgA = vg + (size_t)rA * 2048 + cA * 8;      // + k0 per tile
  const unsigned short* vgB = vg + (size_t)(rA + 8) * 2048 + cA * 8;

  // prologue: stage kt=0 K/V into buffer 0, load kt=0 bias fragments
  gll16(kgA, Ks + w * 1024);
  gll16(kgB, Ks + w * 1024 + 512);
  gll16(vgA, Vs + w * 1024);
  gll16(vgB, Vs + w * 1024 + 512);
  u16x8 bu_lo = *(const u16x8*)(bgt);
  u16x8 bu_hi = *(const u16x8*)(bgt + 8);
  u16x8 bun_lo = bu_lo, bun_hi = bu_hi;

  __syncthreads();

  bf16x8 qf[2];
#pragma unroll
  for (int hh = 0; hh < 2; ++hh)
    qf[hh] = *(const bf16x8*)&QPs[(16 * w + lx) * 64 + hh * 32 + quad * 8];

  float l_run[4] = {0.f, 0.f, 0.f, 0.f};
  f32x4 acco[4];
#pragma unroll
  for (int j = 0; j < 4; ++j) acco[j] = (f32x4){0.f, 0.f, 0.f, 0.f};

  for (int kt = 0; kt < 32; ++kt) {
    const int cur = kt & 1;
    const unsigned short* kc = Ks + cur * 4096;
    const unsigned short* vc = Vs + cur * 4096;
    // issue next tile's DMA + bias prefetch before computing current tile
    if (kt < 31) {
      const size_t k1 = (size_t)(kt + 1) * 64;
      unsigned short* kn = Ks + (cur ^ 1) * 4096 + w * 1024;
      unsigned short* vn = Vs + (cur ^ 1) * 4096 + w * 1024;
      gll16(kgA + k1 * 64, kn);
      gll16(kgB + k1 * 64, kn + 512);
      gll16(vgA + k1, vn);
      gll16(vgB + k1, vn + 512);
      bun_lo = *(const u16x8*)(bgt + (size_t)(kt + 1) * 1024);
      bun_hi = *(const u16x8*)(bgt + (size_t)(kt + 1) * 1024 + 8);
    }

    // accs[j][rr] init from fragment-tiled bias: idx = j*4+rr
    f32x4 accs[4];
#pragma unroll
    for (int j = 0; j < 4; ++j)
#pragma unroll
      for (int rr = 0; rr < 4; ++rr)
        accs[j][rr] = bf2f((j < 2) ? bu_lo[(j & 1) * 4 + rr] : bu_hi[(j & 1) * 4 + rr]);
    __builtin_amdgcn_s_setprio(1);
#pragma unroll
    for (int j = 0; j < 4; ++j) {
#pragma unroll
      for (int hh = 0; hh < 2; ++hh) {
        bf16x8 kf = *(const bf16x8*)&kc[(j * 16 + lx) * 64 + ((hh * 4 + quad) ^ lx7) * 8];
        accs[j] = __builtin_amdgcn_mfma_f32_16x16x32_bf16(qf[hh], kf, accs[j], 0, 0, 0);
      }
    }
    __builtin_amdgcn_s_setprio(0);

    // fixed-reference softmax: p = exp2(score), per-lane partial l, no max
#pragma unroll
    for (int rr = 0; rr < 4; ++rr) {
      float p0 = __builtin_amdgcn_exp2f(accs[0][rr]);
      float p1 = __builtin_amdgcn_exp2f(accs[1][rr]);
      float p2 = __builtin_amdgcn_exp2f(accs[2][rr]);
      float p3 = __builtin_amdgcn_exp2f(accs[3][rr]);
      l_run[rr] += (p0 + p1) + (p2 + p3);
      // P write: q=quad*4+rr, k=lx+16j; phys chunk = (k>>3) ^ (q&7)
      const int q = quad * 4 + rr;
      const int swz = q & 7;
      const int ch = lx >> 3;
      unsigned short* pw = QPs + w * 1024 + q * 64 + (lx & 7);
      pw[((ch ^ swz) << 3)]       = f2bf(p0);
      pw[(((ch + 2) ^ swz) << 3)] = f2bf(p1);
      pw[(((ch + 4) ^ swz) << 3)] = f2bf(p2);
      pw[(((ch + 6) ^ swz) << 3)] = f2bf(p3);
    }
    __asm__ volatile("s_waitcnt lgkmcnt(0)" ::: "memory");
    bf16x8 pf[2];
#pragma unroll
    for (int kh = 0; kh < 2; ++kh)
      pf[kh] = *(const bf16x8*)&QPs[w * 1024 + lx * 64 + (((kh * 4 + quad) ^ (lx & 7)) << 3)];
    __builtin_amdgcn_s_setprio(1);
#pragma unroll
    for (int j = 0; j < 4; ++j) {
#pragma unroll
      for (int kh = 0; kh < 2; ++kh) {
        bf16x8 vf = *(const bf16x8*)&vc[(j * 16 + lx) * 64 + ((kh * 4 + quad) ^ lx7) * 8];
        acco[j] = __builtin_amdgcn_mfma_f32_16x16x32_bf16(pf[kh], vf, acco[j], 0, 0, 0);
      }
    }
    __builtin_amdgcn_s_setprio(0);
    __syncthreads();   // waves done with buf[cur]; DMA into buf[cur^1] drained here
    bu_lo = bun_lo;
    bu_hi = bun_hi;
  }

  // epilogue: one cross-lane l reduction, O /= l, write ctx[b][s][h][hd] bf16
#pragma unroll
  for (int rr = 0; rr < 4; ++rr) {
    float l = l_run[rr];
#pragma unroll
    for (int d = 1; d < 16; d <<= 1) l += __shfl_xor(l, d, 64);
    float rl = __builtin_amdgcn_rcpf(l);
    int s = q0 + 16 * w + quad * 4 + rr;
    unsigned short* dst = ctx + (((size_t)b * 2048 + s) * 16 + h) * 64;
#pragma unroll
    for (int j = 0; j < 4; ++j) dst[j * 16 + lx] = f2bf(acco[j][rr] * rl);
  }
}

// ---------------------------------------------------------------------------
// Kernel: output GEMM  out[4096][1024] = ctx[4096][1024] @ Wo_t^T + bo  (fp32)
// 128x64 tiles -> 512 blocks (2 blocks/CU).  24KB LDS double-buffered.
// ---------------------------------------------------------------------------
__global__ __launch_bounds__(256) void k_out(const unsigned short* __restrict__ cx,
                                             const unsigned short* __restrict__ wt,
                                             const float* __restrict__ bo,
                                             float* __restrict__ out) {
  __shared__ __align__(16) unsigned short As[8192];  // 2 x [128 m][32 k]
  __shared__ __align__(16) unsigned short Bs[4096];  // 2 x [ 64 n][32 k]
  const int tid = threadIdx.x;
  const int w = tid >> 6, lane = tid & 63, quad = lane >> 4, lx = lane & 15;
  const int m0 = blockIdx.y * 128, n0 = blockIdx.x * 64;
  const int wrow = w >> 1, wcol = w & 1;

  f32x4 acc[4][2];
#pragma unroll
  for (int i = 0; i < 4; ++i)
#pragma unroll
    for (int j = 0; j < 2; ++j) acc[i][j] = (f32x4){0.f, 0.f, 0.f, 0.f};

  const unsigned short* ga = cx + (size_t)(m0 + 32 * w + (lane >> 2)) * 1024 + (lane & 3) * 8;
  const unsigned short* gb = wt + (size_t)(n0 + 16 * w + (lane >> 2)) * 1024 + (lane & 3) * 8;

  gll16(ga, As + w * 1024);
  gll16(ga + 16 * 1024, As + w * 1024 + 512);
  gll16(gb, Bs + w * 512);
  __syncthreads();

  for (int kt = 0; kt < 32; ++kt) {
    const int cur = kt & 1;
    if (kt < 31) {
      const int kofs = (kt + 1) * 32;
      unsigned short* lan = As + (cur ^ 1) * 4096 + w * 1024;
      gll16(ga + kofs, lan);
      gll16(ga + kofs + 16 * 1024, lan + 512);
      gll16(gb + kofs, Bs + (cur ^ 1) * 2048 + w * 512);
    }
    const unsigned short* ac = As + cur * 4096;
    const unsigned short* bc = Bs + cur * 2048;
    bf16x8 af[4], bfr[2];
#pragma unroll
    for (int i = 0; i < 4; ++i)
      af[i] = *(const bf16x8*)&ac[(64 * wrow + 16 * i + lx) * 32 + quad * 8];
#pragma unroll
    for (int j = 0; j < 2; ++j)
      bfr[j] = *(const bf16x8*)&bc[(32 * wcol + 16 * j + lx) * 32 + quad * 8];
    __builtin_amdgcn_s_setprio(1);
#pragma unroll
    for (int i = 0; i < 4; ++i)
#pragma unroll
      for (int j = 0; j < 2; ++j)
        acc[i][j] = __builtin_amdgcn_mfma_f32_16x16x32_bf16(af[i], bfr[j], acc[i][j], 0, 0, 0);
    __builtin_amdgcn_s_setprio(0);
    __syncthreads();
  }

  const int colbase = n0 + 32 * wcol;
  float bb[2];
#pragma unroll
  for (int j = 0; j < 2; ++j) bb[j] = bo[colbase + j * 16 + lx];
#pragma unroll
  for (int i = 0; i < 4; ++i) {
#pragma unroll
    for (int rr = 0; rr < 4; ++rr) {
      int m = m0 + 64 * wrow + 16 * i + quad * 4 + rr;
      float* dst = out + (size_t)m * 1024 + colbase;
#pragma unroll
      for (int j = 0; j < 2; ++j) dst[j * 16 + lx] = acc[i][j][rr] + bb[j];
    }
  }
}

// ---------------------------------------------------------------------------
extern "C" void kernel_launch(void* const* d_in, const int* in_sizes, int n_in,
                              void* d_out, int out_size, void* d_ws, size_t ws_size,
                              hipStream_t stream) {
  (void)in_sizes; (void)n_in; (void)out_size; (void)ws_size;
  const float* x   = (const float*)d_in[0];
  const float* Qb  = (const float*)d_in[1];
  const float* Wq  = (const float*)d_in[2];
  const float* bq  = (const float*)d_in[3];
  const float* Wk  = (const float*)d_in[4];
  const float* bk  = (const float*)d_in[5];
  const float* Wv  = (const float*)d_in[6];
  const float* bv  = (const float*)d_in[7];
  const float* qls = (const float*)d_in[8];
  const float* kls = (const float*)d_in[9];
  const float* Ra  = (const float*)d_in[10];
  const float* Wo  = (const float*)d_in[11];
  const float* bo  = (const float*)d_in[12];
  float* out = (float*)d_out;

  char* ws = (char*)d_ws;
  unsigned short* xb    = (unsigned short*)(ws + 0);          //  8 MB  [4096][1024]
  unsigned short* wqkvt = (unsigned short*)(ws + 8388608);    //  6 MB  [3072][1024]
  unsigned short* wot   = (unsigned short*)(ws + 14680064);   //  2 MB  [1024][1024]
  unsigned short* qb    = (unsigned short*)(ws + 16777216);   //  8 MB  [b][h][s][hd]
  unsigned short* kb    = (unsigned short*)(ws + 25165824);   //  8 MB  [b][h][s][hd]
  unsigned short* vtb   = (unsigned short*)(ws + 33554432);   //  8 MB  [b][h][hd][s]
  unsigned short* ctxb  = (unsigned short*)(ws + 41943040);   //  8 MB  [b][s][h][hd]
  unsigned short* biasb = (unsigned short*)(ws + 50331648);   // 134 MB fragment-tiled

  k_pre<<<8192, 256, 0, stream>>>(x, Wq, Wk, Wv, Wo, xb, wqkvt, wot);
  k_qkv_bias<<<4864, 256, 0, stream>>>(xb, wqkvt, bq, bk, bv, qls, kls,
                                       qb, kb, vtb, Qb, Ra, biasb);
  k_attn<<<dim3(32, 16, 2), 256, 0, stream>>>(qb, kb, vtb, biasb, ctxb);
  k_out<<<dim3(16, 32), 256, 0, stream>>>(ctxb, wot, bo, out);
}